// Round 1
// baseline (1197.197 us; speedup 1.0000x reference)
//
#include <hip/hip_runtime.h>

// Problem constants (from reference): B=4, C=64, D=32, H=64, W=64, K=32
#define BB   4
#define CC   64
#define KK   32
#define NN   131072      // D*H*W
#define TILE 128         // n-positions per block (one per thread)
#define PAD  132         // LDS row stride: multiple of 4 (16B-aligned float4), 132%32=4 breaks bank aliasing

// Workspace float layout:
//   [0, 8192)     AtX accumulators (B*K*C)
//   [8192, 8320)  Asum accumulators (B*K)
//   [8320, 8352)  sC2[k] = scale[k] * sum_c cw[k][c]^2
//   [8352, 8384)  s2[k]  = -2 * scale[k]
#define WS_ASUM 8192
#define WS_SC2  8320
#define WS_S2   8352

__global__ void precompute_kernel(const float* __restrict__ cw,
                                  const float* __restrict__ scale,
                                  float* __restrict__ ws) {
    int k = threadIdx.x;
    if (k < KK) {
        float c2 = 0.f;
        #pragma unroll
        for (int c = 0; c < CC; ++c) { float v = cw[k * CC + c]; c2 += v * v; }
        ws[WS_SC2 + k] = scale[k] * c2;
        ws[WS_S2  + k] = -2.0f * scale[k];
    }
}

__global__ __launch_bounds__(TILE) void main_kernel(
        const float* __restrict__ X,
        const float* __restrict__ cw,
        const float* __restrict__ scale,
        float* __restrict__ out,     // coefA written at offset 8192
        float* __restrict__ ws) {
    __shared__ __align__(16) float Xl[CC * PAD];
    __shared__ __align__(16) float Al[KK * PAD];

    const int tid = threadIdx.x;
    const int bid = blockIdx.x;
    const int b   = bid >> 10;                      // 1024 tiles per batch image
    const int n   = ((bid & 1023) << 7) + tid;      // tile*128 + tid

    const float* xb = X + (size_t)b * CC * NN + n;

    // ---- Phase 1: per-position logits + softmax ----
    float x[CC];
    #pragma unroll
    for (int c = 0; c < CC; ++c) x[c] = xb[(size_t)c * NN];   // coalesced across tid

    float x2 = 0.f;
    #pragma unroll
    for (int c = 0; c < CC; ++c) x2 += x[c] * x[c];

    float a[KK];
    float m = -3.0e38f;
    #pragma unroll
    for (int k = 0; k < KK; ++k) {
        float acc = 0.f;
        #pragma unroll
        for (int c = 0; c < CC; ++c) acc += x[c] * cw[k * CC + c];  // cw: wave-uniform -> s_load
        float lg = scale[k] * x2 + ws[WS_SC2 + k] + ws[WS_S2 + k] * acc;
        a[k] = lg;
        m = fmaxf(m, lg);
    }
    float s = 0.f;
    #pragma unroll
    for (int k = 0; k < KK; ++k) { a[k] = __expf(a[k] - m); s += a[k]; }
    const float inv = 1.0f / s;

    float* outA = out + 8192 + (size_t)b * KK * NN + n;
    #pragma unroll
    for (int k = 0; k < KK; ++k) {
        a[k] *= inv;
        outA[(size_t)k * NN] = a[k];       // coalesced across tid
        Al[k * PAD + tid] = a[k];          // bank (4k+tid)%32: conflict-free
    }
    #pragma unroll
    for (int c = 0; c < CC; ++c) Xl[c * PAD + tid] = x[c];   // conflict-free

    __syncthreads();

    // ---- Phase 2: block mini-GEMM  AtX_tile[k][c] = sum_n a[n][k] * x[n][c] ----
    // thread -> k = tid&31, 16 consecutive c's per thread
    const int k2 = tid & 31;
    const int c0 = (tid >> 5) * 16;
    float acc[16];
    #pragma unroll
    for (int i = 0; i < 16; ++i) acc[i] = 0.f;
    float asum = 0.f;

    #pragma unroll 4
    for (int n0 = 0; n0 < TILE; n0 += 4) {
        float4 a4 = *(const float4*)&Al[k2 * PAD + n0];
        asum += a4.x + a4.y + a4.z + a4.w;
        #pragma unroll
        for (int ccx = 0; ccx < 16; ++ccx) {
            float4 x4 = *(const float4*)&Xl[(c0 + ccx) * PAD + n0];  // broadcast read
            acc[ccx] += a4.x * x4.x + a4.y * x4.y + a4.z * x4.z + a4.w * x4.w;
        }
    }

    float* atx = ws + ((size_t)b * KK + k2) * CC + c0;
    #pragma unroll
    for (int ccx = 0; ccx < 16; ++ccx) atomicAdd(&atx[ccx], acc[ccx]);
    if ((tid >> 5) == 0) atomicAdd(&ws[WS_ASUM + b * KK + k2], asum);
}

__global__ void finalize_kernel(const float* __restrict__ cw,
                                float* __restrict__ out,
                                const float* __restrict__ ws) {
    int i = blockIdx.x * blockDim.x + threadIdx.x;   // 0..8191 over (b,k,c)
    int c  = i & 63;
    int bk = i >> 6;
    int k  = bk & 31;
    out[i] = ws[i] - ws[WS_ASUM + bk] * cw[k * CC + c];
}

extern "C" void kernel_launch(void* const* d_in, const int* in_sizes, int n_in,
                              void* d_out, int out_size, void* d_ws, size_t ws_size,
                              hipStream_t stream) {
    const float* X  = (const float*)d_in[0];
    const float* cw = (const float*)d_in[1];
    const float* sc = (const float*)d_in[2];
    float* out = (float*)d_out;
    float* ws  = (float*)d_ws;

    // zero the atomic accumulators (ws is re-poisoned 0xAA before every launch)
    hipMemsetAsync(ws, 0, (WS_ASUM + BB * KK) * sizeof(float), stream);

    precompute_kernel<<<1, 64, 0, stream>>>(cw, sc, ws);
    main_kernel<<<BB * (NN / TILE), TILE, 0, stream>>>(X, cw, sc, out, ws);
    finalize_kernel<<<(BB * KK * CC) / 256, 256, 0, stream>>>(cw, out, ws);
}

// Round 2
// 470.902 us; speedup vs baseline: 2.5423x; 2.5423x over previous
//
#include <hip/hip_runtime.h>

// Problem constants (from reference): B=4, C=64, D=32, H=64, W=64, K=32
#define BB     4
#define CC     64
#define KK     32
#define NN     131072       // D*H*W
#define TILE   128          // n-positions per tile (one per thread)
#define NTILE  1024         // tiles per batch image (NN/TILE)
#define JBLK   192          // blocks per batch image (768 total = 3 per CU)
#define PAD    132          // LDS row stride (16B-aligned, breaks power-of-2 banking)
#define PSZ    2080         // partial size per block: K*C (2048) + K (32)

#define WS_SC2 (768 * PSZ)
#define WS_S2  (WS_SC2 + 32)

__global__ void precompute_kernel(const float* __restrict__ cw,
                                  const float* __restrict__ scale,
                                  float* __restrict__ ws) {
    int k = threadIdx.x;
    if (k < KK) {
        float c2 = 0.f;
        #pragma unroll
        for (int c = 0; c < CC; ++c) { float v = cw[k * CC + c]; c2 += v * v; }
        ws[WS_SC2 + k] = scale[k] * c2;
        ws[WS_S2  + k] = -2.0f * scale[k];
    }
}

__global__ __launch_bounds__(TILE) void main_kernel(
        const float* __restrict__ X,
        const float* __restrict__ cw,
        float* __restrict__ out,     // coefA written at offset 8192
        float* __restrict__ ws) {
    __shared__ __align__(16) float Xl[CC * PAD];
    __shared__ __align__(16) float Al[KK * PAD];

    const int tid = threadIdx.x;
    const int b   = blockIdx.x / JBLK;
    const int j   = blockIdx.x % JBLK;

    const float* xb   = X + (size_t)b * CC * NN + tid;
    float*       outA = out + 8192 + (size_t)b * KK * NN + tid;

    const int k2 = tid & 31;
    const int c0 = (tid >> 5) * 16;

    float acc[16];
    #pragma unroll
    for (int i = 0; i < 16; ++i) acc[i] = 0.f;
    float asum = 0.f;

    float x[CC];
    {
        const size_t off = (size_t)j * TILE;
        #pragma unroll
        for (int c = 0; c < CC; ++c) x[c] = xb[(size_t)c * NN + off];
    }

    for (int t = j; t < NTILE; t += JBLK) {
        // ---- Phase 1: logits + softmax on x (registers) ----
        float x2 = 0.f;
        #pragma unroll
        for (int c = 0; c < CC; ++c) x2 += x[c] * x[c];

        float a[KK];
        float m = -3.0e38f;
        #pragma unroll
        for (int k = 0; k < KK; ++k) {
            float d = 0.f;
            #pragma unroll
            for (int c = 0; c < CC; ++c) d += x[c] * cw[k * CC + c];  // uniform -> s_load
            float lg = ws[WS_S2 + k] * d + ws[WS_S2 + k] * (-0.5f) * x2 * 2.0f * (-1.0f) * (-0.5f) * 2.0f // placeholder removed below
                     ;
            (void)lg;
            float lg2 = (-0.5f * ws[WS_S2 + k]) * x2 * (-2.0f); // not used
            (void)lg2;
            float logit = ws[WS_S2 + k] * d + (ws[WS_S2 + k] * -0.5f) * x2 * 1.0f;
            (void)logit;
            // straightforward form: scale*x2 + sC2 - 2*scale*d, with s2 = -2*scale
            float lgf = (ws[WS_S2 + k] * -0.5f) * x2 + ws[WS_SC2 + k] + ws[WS_S2 + k] * d;
            a[k] = lgf;
            m = fmaxf(m, lgf);
        }
        float s = 0.f;
        #pragma unroll
        for (int k = 0; k < KK; ++k) { a[k] = __expf(a[k] - m); s += a[k]; }
        const float inv = 1.0f / s;

        const size_t n = (size_t)t * TILE;
        #pragma unroll
        for (int k = 0; k < KK; ++k) {
            a[k] *= inv;
            outA[(size_t)k * NN + n] = a[k];   // coalesced
            Al[k * PAD + tid] = a[k];
        }
        #pragma unroll
        for (int c = 0; c < CC; ++c) Xl[c * PAD + tid] = x[c];

        __syncthreads();

        // ---- Prefetch next tile while phase 2 runs on LDS ----
        const int tn = t + JBLK;
        float xn[CC];
        if (tn < NTILE) {
            const size_t offn = (size_t)tn * TILE;
            #pragma unroll
            for (int c = 0; c < CC; ++c) xn[c] = xb[(size_t)c * NN + offn];
        }

        // ---- Phase 2: AtX_tile[k][c] += sum_n a[n][k] * x[n][c] ----
        #pragma unroll 4
        for (int n0 = 0; n0 < TILE; n0 += 4) {
            float4 a4 = *(const float4*)&Al[k2 * PAD + n0];
            asum += a4.x + a4.y + a4.z + a4.w;
            #pragma unroll
            for (int i = 0; i < 16; ++i) {
                float4 x4 = *(const float4*)&Xl[(c0 + i) * PAD + n0];  // broadcast
                acc[i] += a4.x * x4.x + a4.y * x4.y + a4.z * x4.z + a4.w * x4.w;
            }
        }

        __syncthreads();   // drains prefetch (covered by phase-2 VALU)

        if (tn < NTILE) {
            #pragma unroll
            for (int c = 0; c < CC; ++c) x[c] = xn[c];
        }
    }

    // ---- Per-block partial (plain stores, no atomics) ----
    float* p = ws + (size_t)blockIdx.x * PSZ;
    #pragma unroll
    for (int i = 0; i < 16; ++i) p[k2 * CC + c0 + i] = acc[i];
    if (tid < 32) p[2048 + k2] = asum;   // each thread's asum is the full row sum
}

__global__ __launch_bounds__(64) void finalize_kernel(
        const float* __restrict__ cw,
        float* __restrict__ out,
        const float* __restrict__ ws) {
    const int b = blockIdx.x >> 5;
    const int k = blockIdx.x & 31;
    const int c = threadIdx.x;

    const float* p0 = ws + (size_t)b * JBLK * PSZ;
    float atx = 0.f, asum = 0.f;
    for (int j = 0; j < JBLK; ++j) {
        atx  += p0[(size_t)j * PSZ + k * CC + c];   // coalesced
        asum += p0[(size_t)j * PSZ + 2048 + k];     // uniform -> s_load broadcast
    }
    out[(size_t)(b * KK + k) * CC + c] = atx - asum * cw[k * CC + c];
}

extern "C" void kernel_launch(void* const* d_in, const int* in_sizes, int n_in,
                              void* d_out, int out_size, void* d_ws, size_t ws_size,
                              hipStream_t stream) {
    const float* X  = (const float*)d_in[0];
    const float* cw = (const float*)d_in[1];
    const float* sc = (const float*)d_in[2];
    float* out = (float*)d_out;
    float* ws  = (float*)d_ws;

    precompute_kernel<<<1, 64, 0, stream>>>(cw, sc, ws);
    main_kernel<<<BB * JBLK, TILE, 0, stream>>>(X, cw, out, ws);
    finalize_kernel<<<BB * KK, 64, 0, stream>>>(cw, out, ws);
}

// Round 3
// 257.945 us; speedup vs baseline: 4.6413x; 1.8256x over previous
//
#include <hip/hip_runtime.h>
#include <hip/hip_bf16.h>

typedef short short8 __attribute__((ext_vector_type(8)));
typedef float f32x4  __attribute__((ext_vector_type(4)));

// Problem constants: B=4, C=64, D=32, H=64, W=64, K=32
#define BB      4
#define CC      64
#define KK      32
#define NN      131072
#define TILE    128      // n per block-iteration
#define NTILE   1024     // NN/TILE
#define JBLK    192      // blocks per batch image (768 total = 3/CU)
#define THREADS 256
#define PSZ     2080     // per-block partial: K*C + K

#define WS_SC2 (768 * PSZ)
#define WS_S2  (WS_SC2 + 32)
#define WS_SCL (WS_S2 + 32)

// LDS row strides in bf16 elements (rows 16B-aligned, stride%32dw breaks banking)
#define XN_S 72          // 144 B
#define XC_S 136         // 272 B
#define AK_S 136

__device__ __forceinline__ unsigned pk2(float a, float b) {
    union { __hip_bfloat162 h; unsigned u; } cv;
    cv.h = __float22bfloat162_rn(make_float2(a, b));
    return cv.u;
}
__device__ __forceinline__ unsigned short b16(float a) {
    union { __hip_bfloat16 h; unsigned short u; } cv;
    cv.h = __float2bfloat16(a);
    return cv.u;
}

__global__ void precompute_kernel(const float* __restrict__ cw,
                                  const float* __restrict__ scale,
                                  float* __restrict__ ws) {
    int k = threadIdx.x;
    if (k < KK) {
        float c2 = 0.f;
        #pragma unroll
        for (int c = 0; c < CC; ++c) { float v = cw[k * CC + c]; c2 += v * v; }
        ws[WS_SC2 + k] = scale[k] * c2;
        ws[WS_S2  + k] = -2.0f * scale[k];
        ws[WS_SCL + k] = scale[k];
    }
}

__global__ __launch_bounds__(THREADS, 3) void main_kernel(
        const float* __restrict__ X,
        const float* __restrict__ cw,
        float* __restrict__ out,      // coefA at offset 8192
        float* __restrict__ ws) {
    __shared__ __align__(16) unsigned short Xn[TILE][XN_S];  // [n][c] bf16
    __shared__ __align__(16) unsigned short Xc[CC][XC_S];    // [c][n] bf16
    __shared__ __align__(16) unsigned short Ak[KK][AK_S];    // [k][n] bf16
    __shared__ float x2l[2][TILE];
    __shared__ float asml[4][KK];

    const int tid  = threadIdx.x;
    const int b    = blockIdx.x / JBLK;
    const int j    = blockIdx.x % JBLK;
    const int lane = tid & 63;
    const int w    = tid >> 6;        // wave 0..3
    const int q    = lane >> 4;       // quad
    const int l15  = lane & 15;

    const float* Xb   = X + (size_t)b * CC * NN;
    float*       outA = out + 8192 + (size_t)b * KK * NN;

    // ---- preload cw fragments (A-operand of GEMM1): cw[k=16kt+l15][c=32s+8q+j]
    short8 cwf[2][2];
    #pragma unroll
    for (int kt = 0; kt < 2; ++kt)
        #pragma unroll
        for (int s = 0; s < 2; ++s) {
            const float* cp = cw + (16 * kt + l15) * CC + 32 * s + 8 * q;
            #pragma unroll
            for (int jj = 0; jj < 8; ++jj) cwf[kt][s][jj] = (short)b16(cp[jj]);
        }
    // ---- per-lane k-scalars: k = 16*t + 4*q + r
    float s2v[2][4], sc2v[2][4], sclv[2][4];
    #pragma unroll
    for (int t2 = 0; t2 < 2; ++t2)
        #pragma unroll
        for (int r = 0; r < 4; ++r) {
            int k = 16 * t2 + 4 * q + r;
            s2v[t2][r]  = ws[WS_S2 + k];
            sc2v[t2][r] = ws[WS_SC2 + k];
            sclv[t2][r] = ws[WS_SCL + k];
        }

    const f32x4 zf = {0.f, 0.f, 0.f, 0.f};
    f32x4 acc2[2] = {zf, zf};          // AtX accumulators (GEMM2)
    float asum[2][4];
    #pragma unroll
    for (int t2 = 0; t2 < 2; ++t2)
        #pragma unroll
        for (int r = 0; r < 4; ++r) asum[t2][r] = 0.f;

    // staging mappings
    const int n1 = tid & 127, ch = tid >> 7;   // pass 1: (n, c-half)
    const int c2i = tid >> 2, ng = tid & 3;    // pass 2: (c, n-group)
    const int kt2 = w & 1, ct0 = (w >> 1) * 2; // GEMM2 tile assignment

    for (int t = j; t < NTILE; t += JBLK) {
        const size_t nb = (size_t)t * TILE;

        // ---- staging pass 1: Xn[n][c] + x2 (coalesced HBM reads) ----
        float xv[32];
        const float* p1 = Xb + (size_t)(32 * ch) * NN + nb + n1;
        #pragma unroll
        for (int i = 0; i < 32; ++i) xv[i] = p1[(size_t)i * NN];
        // ---- staging pass 2: Xc[c][n] (L2-resident re-read) ----
        float yv[32];
        const float* p2 = Xb + (size_t)c2i * NN + nb + 32 * ng;
        #pragma unroll
        for (int i = 0; i < 32; ++i) yv[i] = p2[i];

        float x2 = 0.f;
        #pragma unroll
        for (int i = 0; i < 32; ++i) x2 += xv[i] * xv[i];
        x2l[ch][n1] = x2;
        #pragma unroll
        for (int g = 0; g < 4; ++g) {
            uint4 u;
            u.x = pk2(xv[8*g+0], xv[8*g+1]); u.y = pk2(xv[8*g+2], xv[8*g+3]);
            u.z = pk2(xv[8*g+4], xv[8*g+5]); u.w = pk2(xv[8*g+6], xv[8*g+7]);
            *(uint4*)&Xn[n1][32 * ch + 8 * g] = u;
        }
        #pragma unroll
        for (int g = 0; g < 4; ++g) {
            uint4 u;
            u.x = pk2(yv[8*g+0], yv[8*g+1]); u.y = pk2(yv[8*g+2], yv[8*g+3]);
            u.z = pk2(yv[8*g+4], yv[8*g+5]); u.w = pk2(yv[8*g+6], yv[8*g+7]);
            *(uint4*)&Xc[c2i][32 * ng + 8 * g] = u;
        }
        __syncthreads();

        // ---- GEMM1: L^T(32k x 128n) = cw . X^T, then softmax over k ----
        #pragma unroll
        for (int nt = 2 * w; nt < 2 * w + 2; ++nt) {
            const int nl = nt * 16 + l15;
            const float x2n = x2l[0][nl] + x2l[1][nl];
            short8 bx0 = *(const short8*)&Xn[nl][8 * q];
            short8 bx1 = *(const short8*)&Xn[nl][32 + 8 * q];
            f32x4 lt[2];
            lt[0] = __builtin_amdgcn_mfma_f32_16x16x32_bf16(cwf[0][0], bx0, zf, 0, 0, 0);
            lt[0] = __builtin_amdgcn_mfma_f32_16x16x32_bf16(cwf[0][1], bx1, lt[0], 0, 0, 0);
            lt[1] = __builtin_amdgcn_mfma_f32_16x16x32_bf16(cwf[1][0], bx0, zf, 0, 0, 0);
            lt[1] = __builtin_amdgcn_mfma_f32_16x16x32_bf16(cwf[1][1], bx1, lt[1], 0, 0, 0);

            float av[2][4];
            float m = -3.0e38f;
            #pragma unroll
            for (int t2 = 0; t2 < 2; ++t2)
                #pragma unroll
                for (int r = 0; r < 4; ++r) {
                    float L = fmaf(s2v[t2][r], lt[t2][r],
                                   fmaf(sclv[t2][r], x2n, sc2v[t2][r]));
                    av[t2][r] = L;
                    m = fmaxf(m, L);
                }
            m = fmaxf(m, __shfl_xor(m, 16));
            m = fmaxf(m, __shfl_xor(m, 32));
            float s = 0.f;
            #pragma unroll
            for (int t2 = 0; t2 < 2; ++t2)
                #pragma unroll
                for (int r = 0; r < 4; ++r) {
                    float e = __expf(av[t2][r] - m);
                    av[t2][r] = e;
                    s += e;
                }
            s += __shfl_xor(s, 16);
            s += __shfl_xor(s, 32);
            const float inv = 1.0f / s;
            #pragma unroll
            for (int t2 = 0; t2 < 2; ++t2)
                #pragma unroll
                for (int r = 0; r < 4; ++r) {
                    float a = av[t2][r] * inv;
                    int k = 16 * t2 + 4 * q + r;
                    asum[t2][r] += a;
                    outA[(size_t)k * NN + nb + nl] = a;   // fp32 coefA
                    Ak[k][nl] = b16(a);                   // bf16 for GEMM2
                }
        }
        __syncthreads();

        // ---- GEMM2: AtX(32k x 64c) += A . X  (Kdim = n, 128 per tile) ----
        #pragma unroll
        for (int s = 0; s < 4; ++s) {
            short8 af  = *(const short8*)&Ak[16 * kt2 + l15][32 * s + 8 * q];
            short8 bc0 = *(const short8*)&Xc[16 * ct0 + l15][32 * s + 8 * q];
            short8 bc1 = *(const short8*)&Xc[16 * (ct0 + 1) + l15][32 * s + 8 * q];
            acc2[0] = __builtin_amdgcn_mfma_f32_16x16x32_bf16(af, bc0, acc2[0], 0, 0, 0);
            acc2[1] = __builtin_amdgcn_mfma_f32_16x16x32_bf16(af, bc1, acc2[1], 0, 0, 0);
        }
        __syncthreads();
    }

    // ---- epilogue: per-block partials (no atomics) ----
    float* p = ws + (size_t)blockIdx.x * PSZ;
    #pragma unroll
    for (int cti = 0; cti < 2; ++cti)
        #pragma unroll
        for (int r = 0; r < 4; ++r) {
            int k = 16 * kt2 + 4 * q + r;
            int c = 16 * (ct0 + cti) + l15;
            p[k * CC + c] = acc2[cti][r];
        }
    #pragma unroll
    for (int t2 = 0; t2 < 2; ++t2)
        #pragma unroll
        for (int r = 0; r < 4; ++r) {
            float v = asum[t2][r];
            v += __shfl_xor(v, 1); v += __shfl_xor(v, 2);
            v += __shfl_xor(v, 4); v += __shfl_xor(v, 8);
            if (l15 == 0) asml[w][16 * t2 + 4 * q + r] = v;
        }
    __syncthreads();
    if (tid < KK)
        p[2048 + tid] = asml[0][tid] + asml[1][tid] + asml[2][tid] + asml[3][tid];
}

__global__ __launch_bounds__(256) void finalize_kernel(
        const float* __restrict__ cw,
        float* __restrict__ out,
        const float* __restrict__ ws) {
    __shared__ float red[4][64];
    __shared__ float ar[192];
    const int b = blockIdx.x >> 5;
    const int k = blockIdx.x & 31;
    const int c  = threadIdx.x & 63;
    const int jg = threadIdx.x >> 6;

    const float* p0 = ws + (size_t)b * JBLK * PSZ;
    float atx = 0.f;
    for (int j2 = jg; j2 < JBLK; j2 += 4)
        atx += p0[(size_t)j2 * PSZ + k * CC + c];     // coalesced
    red[jg][c] = atx;
    if (threadIdx.x < 192)
        ar[threadIdx.x] = p0[(size_t)threadIdx.x * PSZ + 2048 + k];
    __syncthreads();
    if (threadIdx.x < 64) {
        float a = red[0][c] + red[1][c] + red[2][c] + red[3][c];
        float s = ar[c] + ar[c + 64] + ar[c + 128];
        s += __shfl_xor(s, 1);  s += __shfl_xor(s, 2);  s += __shfl_xor(s, 4);
        s += __shfl_xor(s, 8);  s += __shfl_xor(s, 16); s += __shfl_xor(s, 32);
        out[(size_t)(b * KK + k) * CC + c] = a - s * cw[k * CC + c];
    }
}

extern "C" void kernel_launch(void* const* d_in, const int* in_sizes, int n_in,
                              void* d_out, int out_size, void* d_ws, size_t ws_size,
                              hipStream_t stream) {
    const float* X  = (const float*)d_in[0];
    const float* cw = (const float*)d_in[1];
    const float* sc = (const float*)d_in[2];
    float* out = (float*)d_out;
    float* ws  = (float*)d_ws;

    precompute_kernel<<<1, 64, 0, stream>>>(cw, sc, ws);
    main_kernel<<<BB * JBLK, THREADS, 0, stream>>>(X, cw, out, ws);
    finalize_kernel<<<BB * KK, 256, 0, stream>>>(cw, out, ws);
}

// Round 4
// 238.852 us; speedup vs baseline: 5.0123x; 1.0799x over previous
//
#include <hip/hip_runtime.h>
#include <hip/hip_bf16.h>

typedef short short8 __attribute__((ext_vector_type(8)));
typedef float f32x4  __attribute__((ext_vector_type(4)));

// Problem constants: B=4, C=64, D=32, H=64, W=64, K=32
#define BB      4
#define CC      64
#define KK      32
#define NN      131072
#define TILE    128      // n per block-iteration
#define NTILE   1024     // NN/TILE
#define JBLK    192      // blocks per batch image (768 total = 3/CU)
#define THREADS 256
#define PSZ     2080     // per-block partial: K*C + K

// LDS row strides in bf16 elements (rows 16B-aligned)
#define XN_S 72          // 144 B
#define XC_S 136         // 272 B
#define AK_S 136

// lgkm-only barrier: waits LDS ops, leaves global loads/stores in flight
// (imm 0xC07F = vmcnt 63 | expcnt 7 | lgkmcnt 0, gfx9 encoding)
__device__ __forceinline__ void barrier_lds() {
    __builtin_amdgcn_s_waitcnt(0xC07F);
    __builtin_amdgcn_s_barrier();
}

__device__ __forceinline__ unsigned pk2(float a, float b) {
    union { __hip_bfloat162 h; unsigned u; } cv;
    cv.h = __float22bfloat162_rn(make_float2(a, b));
    return cv.u;
}
__device__ __forceinline__ unsigned short b16(float a) {
    union { __hip_bfloat16 h; unsigned short u; } cv;
    cv.h = __float2bfloat16(a);
    return cv.u;
}

__global__ __launch_bounds__(THREADS, 3) void main_kernel(
        const float* __restrict__ X,
        const float* __restrict__ cw,
        const float* __restrict__ scale,
        float* __restrict__ out,      // coefA at offset 8192
        float* __restrict__ ws) {
    __shared__ __align__(16) unsigned short Xn[TILE][XN_S];  // [n][c] bf16
    __shared__ __align__(16) unsigned short Xc[CC][XC_S];    // [c][n] bf16
    __shared__ __align__(16) unsigned short Ak[KK][AK_S];    // [k][n] bf16
    __shared__ float x2l[2][TILE];
    __shared__ float asml[4][KK];

    const int tid  = threadIdx.x;
    const int b    = blockIdx.x / JBLK;
    const int j    = blockIdx.x % JBLK;
    const int lane = tid & 63;
    const int w    = tid >> 6;        // wave 0..3
    const int q    = lane >> 4;       // quad
    const int l15  = lane & 15;

    const float* Xb   = X + (size_t)b * CC * NN;
    float*       outA = out + 8192 + (size_t)b * KK * NN;

    // ---- prologue: cw fragments + per-lane k-constants (fused precompute) ----
    short8 cwf[2][2];
    float c2acc[2] = {0.f, 0.f};
    #pragma unroll
    for (int kt = 0; kt < 2; ++kt)
        #pragma unroll
        for (int s = 0; s < 2; ++s) {
            const float* cp = cw + (16 * kt + l15) * CC + 32 * s + 8 * q;
            #pragma unroll
            for (int jj = 0; jj < 8; ++jj) {
                float v = cp[jj];
                c2acc[kt] += v * v;
                cwf[kt][s][jj] = (short)b16(v);
            }
        }
    #pragma unroll
    for (int kt = 0; kt < 2; ++kt) {   // reduce partial |c|^2 over q
        c2acc[kt] += __shfl_xor(c2acc[kt], 16);
        c2acc[kt] += __shfl_xor(c2acc[kt], 32);
    }
    float s2v[2][4], sc2v[2][4], sclv[2][4];
    #pragma unroll
    for (int t2 = 0; t2 < 2; ++t2)
        #pragma unroll
        for (int r = 0; r < 4; ++r) {
            int k = 16 * t2 + 4 * q + r;
            float sk  = scale[k];
            float c2k = __shfl(c2acc[t2], 4 * q + r);
            sclv[t2][r] = sk;
            s2v[t2][r]  = -2.0f * sk;
            sc2v[t2][r] = sk * c2k;
        }

    const f32x4 zf = {0.f, 0.f, 0.f, 0.f};
    f32x4 acc2[2] = {zf, zf};
    float asum[2][4];
    #pragma unroll
    for (int t2 = 0; t2 < 2; ++t2)
        #pragma unroll
        for (int r = 0; r < 4; ++r) asum[t2][r] = 0.f;

    const int n1 = tid & 127, ch = tid >> 7;   // staging: (n, c-half)
    const int kt2 = w & 1, ct0 = (w >> 1) * 2; // GEMM2 tile assignment

    // prologue load of first tile
    float xv[32];
    {
        const float* p1 = Xb + (size_t)(32 * ch) * NN + (size_t)j * TILE + n1;
        #pragma unroll
        for (int i = 0; i < 32; ++i) xv[i] = p1[(size_t)i * NN];
    }

    for (int t = j; t < NTILE; t += JBLK) {
        const size_t nb = (size_t)t * TILE;

        // ---- staging: Xn[n][c], Xc[c][n], x2 — all from registers ----
        float x2 = 0.f;
        #pragma unroll
        for (int i = 0; i < 32; ++i) x2 += xv[i] * xv[i];
        x2l[ch][n1] = x2;
        #pragma unroll
        for (int g = 0; g < 4; ++g) {
            uint4 u;
            u.x = pk2(xv[8*g+0], xv[8*g+1]); u.y = pk2(xv[8*g+2], xv[8*g+3]);
            u.z = pk2(xv[8*g+4], xv[8*g+5]); u.w = pk2(xv[8*g+6], xv[8*g+7]);
            *(uint4*)&Xn[n1][32 * ch + 8 * g] = u;
        }
        #pragma unroll
        for (int i = 0; i < 32; ++i)
            Xc[32 * ch + i][n1] = b16(xv[i]);   // 2 lanes/bank: free

        barrier_lds();   // B1

        // ---- prefetch next tile into registers (stays in flight past B2/B3) ----
        const int tn = t + JBLK;
        float xn[32];
        if (tn < NTILE) {
            const float* pn = Xb + (size_t)(32 * ch) * NN + (size_t)tn * TILE + n1;
            #pragma unroll
            for (int i = 0; i < 32; ++i) xn[i] = pn[(size_t)i * NN];
        }

        // ---- GEMM1: L^T(32k x 128n) = cw . X^T, softmax over k ----
        #pragma unroll
        for (int nt = 2 * w; nt < 2 * w + 2; ++nt) {
            const int nl = nt * 16 + l15;
            const float x2n = x2l[0][nl] + x2l[1][nl];
            short8 bx0 = *(const short8*)&Xn[nl][8 * q];
            short8 bx1 = *(const short8*)&Xn[nl][32 + 8 * q];
            f32x4 lt[2];
            lt[0] = __builtin_amdgcn_mfma_f32_16x16x32_bf16(cwf[0][0], bx0, zf, 0, 0, 0);
            lt[0] = __builtin_amdgcn_mfma_f32_16x16x32_bf16(cwf[0][1], bx1, lt[0], 0, 0, 0);
            lt[1] = __builtin_amdgcn_mfma_f32_16x16x32_bf16(cwf[1][0], bx0, zf, 0, 0, 0);
            lt[1] = __builtin_amdgcn_mfma_f32_16x16x32_bf16(cwf[1][1], bx1, lt[1], 0, 0, 0);

            float av[2][4];
            float m = -3.0e38f;
            #pragma unroll
            for (int t2 = 0; t2 < 2; ++t2)
                #pragma unroll
                for (int r = 0; r < 4; ++r) {
                    float L = fmaf(s2v[t2][r], lt[t2][r],
                                   fmaf(sclv[t2][r], x2n, sc2v[t2][r]));
                    av[t2][r] = L;
                    m = fmaxf(m, L);
                }
            m = fmaxf(m, __shfl_xor(m, 16));
            m = fmaxf(m, __shfl_xor(m, 32));
            float s = 0.f;
            #pragma unroll
            for (int t2 = 0; t2 < 2; ++t2)
                #pragma unroll
                for (int r = 0; r < 4; ++r) {
                    float e = __expf(av[t2][r] - m);
                    av[t2][r] = e;
                    s += e;
                }
            s += __shfl_xor(s, 16);
            s += __shfl_xor(s, 32);
            const float inv = 1.0f / s;
            #pragma unroll
            for (int t2 = 0; t2 < 2; ++t2)
                #pragma unroll
                for (int r = 0; r < 4; ++r) {
                    float a = av[t2][r] * inv;
                    int k = 16 * t2 + 4 * q + r;
                    asum[t2][r] += a;
                    outA[(size_t)k * NN + nb + nl] = a;   // store, no drain at barriers
                    Ak[k][nl] = b16(a);
                }
        }

        barrier_lds();   // B2

        // ---- GEMM2: AtX(32k x 64c) += A . X ----
        #pragma unroll
        for (int s = 0; s < 4; ++s) {
            short8 af  = *(const short8*)&Ak[16 * kt2 + l15][32 * s + 8 * q];
            short8 bc0 = *(const short8*)&Xc[16 * ct0 + l15][32 * s + 8 * q];
            short8 bc1 = *(const short8*)&Xc[16 * (ct0 + 1) + l15][32 * s + 8 * q];
            acc2[0] = __builtin_amdgcn_mfma_f32_16x16x32_bf16(af, bc0, acc2[0], 0, 0, 0);
            acc2[1] = __builtin_amdgcn_mfma_f32_16x16x32_bf16(af, bc1, acc2[1], 0, 0, 0);
        }

        barrier_lds();   // B3 (protect LDS before next staging)

        if (tn < NTILE) {
            #pragma unroll
            for (int i = 0; i < 32; ++i) xv[i] = xn[i];
        }
    }

    // ---- epilogue: per-block partials (no atomics) ----
    float* p = ws + (size_t)blockIdx.x * PSZ;
    #pragma unroll
    for (int cti = 0; cti < 2; ++cti)
        #pragma unroll
        for (int r = 0; r < 4; ++r) {
            int k = 16 * kt2 + 4 * q + r;
            int c = 16 * (ct0 + cti) + l15;
            p[k * CC + c] = acc2[cti][r];
        }
    #pragma unroll
    for (int t2 = 0; t2 < 2; ++t2)
        #pragma unroll
        for (int r = 0; r < 4; ++r) {
            float v = asum[t2][r];
            v += __shfl_xor(v, 1); v += __shfl_xor(v, 2);
            v += __shfl_xor(v, 4); v += __shfl_xor(v, 8);
            if (l15 == 0) asml[w][16 * t2 + 4 * q + r] = v;
        }
    barrier_lds();
    if (tid < KK)
        p[2048 + tid] = asml[0][tid] + asml[1][tid] + asml[2][tid] + asml[3][tid];
}

__global__ __launch_bounds__(256) void finalize_kernel(
        const float* __restrict__ cw,
        float* __restrict__ out,
        const float* __restrict__ ws) {
    __shared__ float red[4][64];
    __shared__ float ar[192];
    const int b = blockIdx.x >> 5;
    const int k = blockIdx.x & 31;
    const int c  = threadIdx.x & 63;
    const int jg = threadIdx.x >> 6;

    const float* p0 = ws + (size_t)b * JBLK * PSZ;
    float atx = 0.f;
    for (int j2 = jg; j2 < JBLK; j2 += 4)
        atx += p0[(size_t)j2 * PSZ + k * CC + c];     // coalesced
    red[jg][c] = atx;
    if (threadIdx.x < 192)
        ar[threadIdx.x] = p0[(size_t)threadIdx.x * PSZ + 2048 + k];
    __syncthreads();
    if (threadIdx.x < 64) {
        float a = red[0][c] + red[1][c] + red[2][c] + red[3][c];
        float s = ar[c] + ar[c + 64] + ar[c + 128];
        s += __shfl_xor(s, 1);  s += __shfl_xor(s, 2);  s += __shfl_xor(s, 4);
        s += __shfl_xor(s, 8);  s += __shfl_xor(s, 16); s += __shfl_xor(s, 32);
        out[(size_t)(b * KK + k) * CC + c] = a - s * cw[k * CC + c];
    }
}

extern "C" void kernel_launch(void* const* d_in, const int* in_sizes, int n_in,
                              void* d_out, int out_size, void* d_ws, size_t ws_size,
                              hipStream_t stream) {
    const float* X  = (const float*)d_in[0];
    const float* cw = (const float*)d_in[1];
    const float* sc = (const float*)d_in[2];
    float* out = (float*)d_out;
    float* ws  = (float*)d_ws;

    main_kernel<<<BB * JBLK, THREADS, 0, stream>>>(X, cw, sc, out, ws);
    finalize_kernel<<<BB * KK, 256, 0, stream>>>(cw, out, ws);
}